// Round 6
// baseline (291.406 us; speedup 1.0000x reference)
//
#include <hip/hip_runtime.h>
#include <stdint.h>

typedef __attribute__((ext_vector_type(4))) float  f32x4;
typedef __attribute__((ext_vector_type(8))) __bf16 bf16x8;

#define NB   32
#define CC   512
#define DD   512
#define HW   1024

static __device__ __forceinline__ uint32_t f2bf(float x) {
    uint32_t u = __float_as_uint(x);
    return (u + 0x7FFFu + ((u >> 16) & 1u)) >> 16;   // RNE bf16
}

// ---------------- softmax over last dim of atts -> bf16 W in ws -------------
__global__ __launch_bounds__(256) void softmax_rows(
        const float* __restrict__ atts, unsigned short* __restrict__ W) {
    const int tid  = threadIdx.x;
    const int wid  = tid >> 6;
    const int lane = tid & 63;
    const int row  = blockIdx.x * 4 + wid;          // 0..16383
    const float* a = atts + (size_t)row * DD;

    float4 v0 = *(const float4*)(a + lane * 4);
    float4 v1 = *(const float4*)(a + 256 + lane * 4);
    float e[8] = {v0.x, v0.y, v0.z, v0.w, v1.x, v1.y, v1.z, v1.w};

    float m = e[0];
    #pragma unroll
    for (int j = 1; j < 8; ++j) m = fmaxf(m, e[j]);
    #pragma unroll
    for (int s = 1; s < 64; s <<= 1) m = fmaxf(m, __shfl_xor(m, s, 64));

    float sum = 0.f;
    #pragma unroll
    for (int j = 0; j < 8; ++j) { e[j] = __expf(e[j] - m); sum += e[j]; }
    #pragma unroll
    for (int s = 1; s < 64; s <<= 1) sum += __shfl_xor(sum, s, 64);
    const float inv = 1.0f / sum;

    uint32_t p[4];
    #pragma unroll
    for (int j = 0; j < 4; ++j)
        p[j] = f2bf(e[2*j] * inv) | (f2bf(e[2*j+1] * inv) << 16);

    unsigned short* wr = W + (size_t)row * DD;
    uint2 q0 = {p[0], p[1]};
    uint2 q1 = {p[2], p[3]};
    *(uint2*)(wr + lane * 4)       = q0;
    *(uint2*)(wr + 256 + lane * 4) = q1;
}

// ---------------- batched GEMM: out[n] = W[n] (512x512) x images[n] (512x1024)
// Barrier-free wave-autonomous design:
//   each wave owns a 128x64 output tile (acc[8][4]) and a PRIVATE LDS slice.
//   A fragments: direct global->VGPR 16B loads (bf16 W, MFMA-A layout).
//   B tile 32x64: reg-staged fp32 -> cvt -> wave-private double-buffered LDS
//   (only needed for the k-transpose). No __syncthreads / s_barrier anywhere;
//   the compiler's per-register s_waitcnt does all pipelining across the
//   8 independent waves per CU.
__global__ __launch_bounds__(256, 2) void gemm_kernel(
        const float* __restrict__ images, const unsigned short* __restrict__ W,
        float* __restrict__ out) {
    // [wave][buf][kgl(4)][col(64, XOR-swizzled)][8 k-elems] bf16 = 32 KB/block
    __shared__ unsigned short lB[4][2][2048];

    // XCD affinity: all 16 wave-tiles... blocks of batch n land on XCD n%8
    const int b  = blockIdx.x;       // 0..511
    const int g  = b & 7;
    const int i  = b >> 3;           // 0..63
    const int n  = (i >> 4) * 8 + g; // batch 0..31
    const int t  = i & 15;
    const int rt = t >> 2;           // row tile 0..3   (128 rows each)
    const int cg = t & 3;            // col group 0..3  (256 cols each)

    const int tid  = threadIdx.x;
    const int w    = tid >> 6;       // wave 0..3 -> 64-col slice of col group
    const int lane = tid & 63;
    const int r15  = lane & 15;
    const int kgl  = lane >> 4;

    const unsigned short* gA = W + (size_t)n * CC * DD + (size_t)(rt * 128) * DD;
    const float*          gB = images + (size_t)n * DD * HW + cg * 256 + w * 64;
    float*                gO = out + (size_t)n * CC * HW + (size_t)(rt * 128) * HW
                                   + cg * 256 + w * 64;

    unsigned short* myB0 = &lB[w][0][0];
    unsigned short* myB1 = &lB[w][1][0];

    f32x4  acc[8][4] = {};
    bf16x8 af[8];
    f32x4  breg[8];

    // A fragment loads: lane (kgl,r15) reads 16B of row (m*16+r15), k=kgl*8
    auto loadA = [&](int ks) {
        const unsigned short* p = gA + (size_t)r15 * DD + ks * 32 + kgl * 8;
        #pragma unroll
        for (int m = 0; m < 8; ++m)
            af[m] = *(const bf16x8*)(p + (size_t)(m * 16) * DD);
    };
    // B loads: lane (kgl,r15) reads rows kgl*8+j (j=0..7), cols r15*4..+3
    auto loadB = [&](int ks) {
        const float* p = gB + (size_t)(ks * 32 + kgl * 8) * HW + r15 * 4;
        #pragma unroll
        for (int j = 0; j < 8; ++j)
            breg[j] = *(const f32x4*)(p + (size_t)j * HW);
    };
    // cvt + wave-private LDS write; stored col = c ^ ((c>>3)&3) (2-way banks)
    auto writeB = [&](unsigned short* dst) {
        #pragma unroll
        for (int cc = 0; cc < 4; ++cc) {
            bf16x8 wv;
            #pragma unroll
            for (int j = 0; j < 8; ++j) wv[j] = (__bf16)breg[j][cc];
            const int c  = r15 * 4 + cc;
            const int cs = c ^ ((c >> 3) & 3);
            *(bf16x8*)(dst + kgl * 512 + cs * 8) = wv;
        }
    };
    auto compute = [&](const unsigned short* src) {
        bf16x8 bv[4];
        #pragma unroll
        for (int nf = 0; nf < 4; ++nf) {
            const int c  = nf * 16 + r15;
            const int cs = c ^ ((c >> 3) & 3);
            bv[nf] = *(const bf16x8*)(src + kgl * 512 + cs * 8);
        }
        #pragma unroll
        for (int m = 0; m < 8; ++m)
            #pragma unroll
            for (int nf = 0; nf < 4; ++nf)
                acc[m][nf] = __builtin_amdgcn_mfma_f32_16x16x32_bf16(
                    af[m], bv[nf], acc[m][nf], 0, 0, 0);
    };

    // ---- prologue ----
    loadB(0);
    writeB(myB0);                    // vmcnt wait on breg auto-inserted
    loadA(0);
    loadB(1);

    // ---- main loop, 2 K-steps per iteration (static buffer indices) ----
    // invariant at top: af=A(ks), myB0=B(ks), breg=B(ks+1) in flight
    for (int ks = 0; ks <= 12; ks += 2) {
        compute(myB0);               // A(ks) x B(ks)
        loadA(ks + 1);
        writeB(myB1);                // B(ks+1)
        loadB(ks + 2);
        compute(myB1);               // A(ks+1) x B(ks+1)
        loadA(ks + 2);
        writeB(myB0);                // B(ks+2)
        loadB(ks + 3);
    }
    // exit: af=A(14), myB0=B(14), breg=B(15) in flight
    compute(myB0);                   // ks=14
    loadA(15);
    writeB(myB1);
    compute(myB1);                   // ks=15

    // ---- epilogue: C/D layout col=lane&15, row=(lane>>4)*4+r ----
    #pragma unroll
    for (int m = 0; m < 8; ++m)
        #pragma unroll
        for (int nf = 0; nf < 4; ++nf)
            #pragma unroll
            for (int r = 0; r < 4; ++r) {
                const int row = m * 16 + kgl * 4 + r;
                const int col = nf * 16 + r15;
                gO[(size_t)row * HW + col] = acc[m][nf][r];
            }
}

extern "C" void kernel_launch(void* const* d_in, const int* in_sizes, int n_in,
                              void* d_out, int out_size, void* d_ws, size_t ws_size,
                              hipStream_t stream) {
    const float* images = (const float*)d_in[0];
    const float* atts   = (const float*)d_in[1];
    float*       out    = (float*)d_out;
    unsigned short* Wbf = (unsigned short*)d_ws;   // 32*512*512*2 = 16.8 MB

    softmax_rows<<<dim3(NB * CC / 4), dim3(256), 0, stream>>>(atts, Wbf);
    gemm_kernel<<<dim3(NB * 16), dim3(256), 0, stream>>>(images, Wbf, out);
}

// Round 7
// 46.002 us; speedup vs baseline: 6.3346x; 6.3346x over previous
//
#include <hip/hip_runtime.h>
#include <stdint.h>

typedef __attribute__((ext_vector_type(4))) float  f32x4;
typedef __attribute__((ext_vector_type(8))) __bf16 bf16x8;

#define NB   32
#define CC   512
#define DD   512
#define HW   1024
#define BM   256
#define BN   256
#define BK   64

#define WAITV0() asm volatile("s_waitcnt vmcnt(0)" ::: "memory")
#define WAITL()  asm volatile("s_waitcnt lgkmcnt(0)" ::: "memory")
#define BARR()   do { asm volatile("" ::: "memory"); __builtin_amdgcn_s_barrier(); \
                      asm volatile("" ::: "memory"); } while (0)

static __device__ __forceinline__ uint32_t f2bf(float x) {
    uint32_t u = __float_as_uint(x);
    return (u + 0x7FFFu + ((u >> 16) & 1u)) >> 16;   // RNE bf16
}

// ---------------- softmax over last dim of atts -> bf16 W in ws -------------
__global__ __launch_bounds__(256) void softmax_rows(
        const float* __restrict__ atts, unsigned short* __restrict__ W) {
    const int tid  = threadIdx.x;
    const int wid  = tid >> 6;
    const int lane = tid & 63;
    const int row  = blockIdx.x * 4 + wid;          // 0..16383
    const float* a = atts + (size_t)row * DD;

    float4 v0 = *(const float4*)(a + lane * 4);
    float4 v1 = *(const float4*)(a + 256 + lane * 4);
    float e[8] = {v0.x, v0.y, v0.z, v0.w, v1.x, v1.y, v1.z, v1.w};

    float m = e[0];
    #pragma unroll
    for (int j = 1; j < 8; ++j) m = fmaxf(m, e[j]);
    #pragma unroll
    for (int s = 1; s < 64; s <<= 1) m = fmaxf(m, __shfl_xor(m, s, 64));

    float sum = 0.f;
    #pragma unroll
    for (int j = 0; j < 8; ++j) { e[j] = __expf(e[j] - m); sum += e[j]; }
    #pragma unroll
    for (int s = 1; s < 64; s <<= 1) sum += __shfl_xor(sum, s, 64);
    const float inv = 1.0f / sum;

    uint32_t p[4];
    #pragma unroll
    for (int j = 0; j < 4; ++j)
        p[j] = f2bf(e[2*j] * inv) | (f2bf(e[2*j+1] * inv) << 16);

    unsigned short* wr = W + (size_t)row * DD;
    uint2 q0 = {p[0], p[1]};
    uint2 q1 = {p[2], p[3]};
    *(uint2*)(wr + lane * 4)       = q0;
    *(uint2*)(wr + 256 + lane * 4) = q1;
}

// ---------------- batched GEMM: out[n] = W[n] (512x512) x images[n] (512x1024)
// 8-phase-template port (m201 structure): 256x256 tile, BK=64, 8 waves
// (2Mx4N, 128x64 per wave), 1 block/CU, grid 256. Per K-tile 4 phases:
//   {12 ds_read frags | staging slice | BARR | setprio+16 MFMA | BARR}
// Staging: B f32 loads @q0, A gload_lds @q1 (B-first so cvt's auto vmcnt(4)
// keeps A in flight), cvt+ds_write @q3, WAITV(0) for A only at tile end.
__global__ __launch_bounds__(512, 2) void gemm_kernel(
        const float* __restrict__ images, const unsigned short* __restrict__ W,
        float* __restrict__ out) {
    __shared__ unsigned short lA[2][BM * BK];       // 2 x 32KB [row][slot(8)][8]
    __shared__ unsigned short lB[2][8][BN * 8];     // 2 x 32KB [kg][col_s][8]

    // batch->XCD affinity: all 8 tiles of batch n on XCD n%8 (4 batches/XCD)
    const int b  = blockIdx.x;       // 0..255
    const int g  = b & 7;
    const int q  = b >> 3;           // 0..31
    const int n  = (q & 3) * 8 + g;  // batch 0..31, n%8 == XCD
    const int t  = q >> 2;           // 0..7
    const int mt = t >> 2;           // 0..1 (row tile, 256 rows)
    const int nt = t & 3;            // 0..3 (col tile, 256 cols)

    const unsigned short* gA = W + (size_t)n * CC * DD + (size_t)(mt * BM) * DD;
    const float*          gB = images + (size_t)n * DD * HW + nt * BN;
    float*                gO = out + (size_t)n * CC * HW + (size_t)(mt * BM) * HW + nt * BN;

    const int tid  = threadIdx.x;    // 0..511
    const int lane = tid & 63;
    const int wid  = tid >> 6;       // 0..7
    const int wm   = wid >> 2;       // 0..1 -> rows wm*128
    const int wn   = wid & 3;        // 0..3 -> cols wn*64
    const int r15  = lane & 15;
    const int kgl  = lane >> 4;      // 0..3

    // B staging: wave = k-group (8 rows), lane covers 4 cols
    const int bkg = wid;
    const int bc0 = lane * 4;

    f32x4  acc[8][4] = {};
    f32x4  breg[8];

    auto stage_a = [&](int buf, int kt) {
        #pragma unroll
        for (int p = 0; p < 4; ++p) {
            const int idx = p * 512 + tid;          // 0..2047 16B-units
            const int row = idx >> 3;               // 0..255
            const int s   = idx & 7;
            const int kg  = s ^ (row & 7);          // inverse-swizzled source
            const unsigned short* src = gA + (size_t)row * DD + kt * BK + kg * 8;
            __builtin_amdgcn_global_load_lds(
                (const __attribute__((address_space(1))) void*)src,
                (__attribute__((address_space(3))) void*)&lA[buf][idx * 8],
                16, 0, 0);
        }
    };
    auto load_b = [&](int kt) {
        const float* p = gB + (size_t)(kt * BK + bkg * 8) * HW + bc0;
        #pragma unroll
        for (int j = 0; j < 8; ++j)
            breg[j] = *(const f32x4*)(p + (size_t)j * HW);
    };
    auto write_b = [&](int buf) {                   // cvt auto-waits breg vmcnt
        #pragma unroll
        for (int cc = 0; cc < 4; ++cc) {
            bf16x8 wv;
            #pragma unroll
            for (int j = 0; j < 8; ++j) wv[j] = (__bf16)breg[j][cc];
            const int col = bc0 + cc;
            const int cs  = col ^ ((col >> 3) & 7);
            *(bf16x8*)&lB[buf][bkg][cs * 8] = wv;
        }
    };
    // one phase: quadrant (mh: 4 m-frags, nh: 2 n-frags) x kk=0,1 -> 16 MFMA
    auto frags_mfma = [&](int buf, int mh, int nh) {
        bf16x8 af[4][2], bv[2][2];
        #pragma unroll
        for (int m4 = 0; m4 < 4; ++m4)
            #pragma unroll
            for (int kk = 0; kk < 2; ++kk) {
                const int row = wm * 128 + (mh * 4 + m4) * 16 + r15;
                const int s   = (kk * 4 + kgl) ^ (row & 7);
                af[m4][kk] = *(const bf16x8*)&lA[buf][row * 64 + s * 8];
            }
        #pragma unroll
        for (int n2 = 0; n2 < 2; ++n2)
            #pragma unroll
            for (int kk = 0; kk < 2; ++kk) {
                const int col = wn * 64 + (nh * 2 + n2) * 16 + r15;
                const int cs  = col ^ ((col >> 3) & 7);
                bv[n2][kk] = *(const bf16x8*)&lB[buf][kk * 4 + kgl][cs * 8];
            }
        __builtin_amdgcn_s_setprio(1);
        #pragma unroll
        for (int m4 = 0; m4 < 4; ++m4)
            #pragma unroll
            for (int n2 = 0; n2 < 2; ++n2)
                #pragma unroll
                for (int kk = 0; kk < 2; ++kk)
                    acc[mh * 4 + m4][nh * 2 + n2] =
                        __builtin_amdgcn_mfma_f32_16x16x32_bf16(
                            af[m4][kk], bv[n2][kk],
                            acc[mh * 4 + m4][nh * 2 + n2], 0, 0, 0);
        __builtin_amdgcn_s_setprio(0);
    };

    // ---- prologue: tile 0 into buf 0 ----
    load_b(0);                       // 8 vmem (oldest)
    stage_a(0, 0);                   // 4 vmem
    write_b(0);                      // waits breg (leaves A outstanding), ds_writes
    WAITV0();                        // A(0) landed
    WAITL();                         // lB writes visible
    BARR();

    // ---- main loop: 8 K-tiles x 4 phases ----
    #pragma unroll
    for (int kt = 0; kt < 8; ++kt) {
        const int cur = kt & 1, nxt = cur ^ 1;
        // q0: frags(0,0) | issue B(kt+1)
        {
            if (kt < 7) load_b(kt + 1);
            frags_mfma(cur, 0, 0);   // reads issued pre-barrier inside
            BARR();
        }
        // q1: frags(0,1) | issue A(kt+1)
        {
            if (kt < 7) stage_a(nxt, kt + 1);
            frags_mfma(cur, 0, 1);
            BARR();
        }
        // q2: frags(1,0)
        {
            frags_mfma(cur, 1, 0);
            BARR();
        }
        // q3: frags(1,1) | cvt+write B(kt+1) | drain A | barrier
        {
            if (kt < 7) write_b(nxt);
            WAITV0();                // A(kt+1) landed (no-op when kt==7)
            WAITL();                 // lB[nxt] writes + frag reads drained
            BARR();
            frags_mfma(cur, 1, 1);
            BARR();
        }
    }

    // ---- epilogue: C/D layout col=lane&15, row=(lane>>4)*4+r ----
    #pragma unroll
    for (int m = 0; m < 8; ++m)
        #pragma unroll
        for (int nf = 0; nf < 4; ++nf)
            #pragma unroll
            for (int r = 0; r < 4; ++r) {
                const int row = wm * 128 + m * 16 + kgl * 4 + r;
                const int col = wn * 64 + nf * 16 + r15;
                gO[(size_t)row * HW + col] = acc[m][nf][r];
            }
}

extern "C" void kernel_launch(void* const* d_in, const int* in_sizes, int n_in,
                              void* d_out, int out_size, void* d_ws, size_t ws_size,
                              hipStream_t stream) {
    const float* images = (const float*)d_in[0];
    const float* atts   = (const float*)d_in[1];
    float*       out    = (float*)d_out;
    unsigned short* Wbf = (unsigned short*)d_ws;   // 32*512*512*2 = 16.8 MB

    softmax_rows<<<dim3(NB * CC / 4), dim3(256), 0, stream>>>(atts, Wbf);
    gemm_kernel<<<dim3(NB * 8), dim3(512), 0, stream>>>(images, Wbf, out);
}